// Round 1
// baseline (392.973 us; speedup 1.0000x reference)
//
#include <hip/hip_runtime.h>
#include <math.h>

#define B_ 4
#define N_ 50000
#define E_ 800000
#define D_ 64
#define M_ (B_*N_)   // 200000 rows for the linear

typedef _Float16 h4 __attribute__((ext_vector_type(4)));
typedef _Float16 h8 __attribute__((ext_vector_type(8)));
typedef float    f4 __attribute__((ext_vector_type(4)));

// ---------- CSR build ----------
__global__ __launch_bounds__(256) void k_count(const int4* __restrict__ col4, int* __restrict__ cnt) {
  int e = blockIdx.x * 256 + threadIdx.x;
  if (e < E_ / 4) {
    int4 c = col4[e];
    atomicAdd(&cnt[c.x], 1);
    atomicAdd(&cnt[c.y], 1);
    atomicAdd(&cnt[c.z], 1);
    atomicAdd(&cnt[c.w], 1);
  }
}

// block-sum partials + dis = rsqrt(deg+1)
__global__ __launch_bounds__(1024) void k_scan_a(const int* __restrict__ cnt, int* __restrict__ part,
                                                 float* __restrict__ dis) {
  __shared__ int sd[1024];
  int i = blockIdx.x * 1024 + threadIdx.x;
  int v = (i < N_) ? cnt[i] : 0;
  if (i < N_) dis[i] = 1.0f / sqrtf((float)(v + 1));  // +1 self-loop
  sd[threadIdx.x] = v;
  __syncthreads();
  for (int s = 512; s > 0; s >>= 1) {
    if (threadIdx.x < s) sd[threadIdx.x] += sd[threadIdx.x + s];
    __syncthreads();
  }
  if (threadIdx.x == 0) part[blockIdx.x] = sd[0];
}

// exclusive scan -> off; also zero the fill cursors
__global__ __launch_bounds__(1024) void k_scan_c(const int* __restrict__ cnt, const int* __restrict__ part,
                                                 int* __restrict__ off, int* __restrict__ cur) {
  __shared__ int sd[1024];
  __shared__ int base_s;
  int i = blockIdx.x * 1024 + threadIdx.x;
  int v = (i < N_) ? cnt[i] : 0;
  if (threadIdx.x == 0) {
    int b = 0;
    for (int j = 0; j < (int)blockIdx.x; j++) b += part[j];
    base_s = b;
  }
  sd[threadIdx.x] = v;
  __syncthreads();
  for (int s = 1; s < 1024; s <<= 1) {
    int t = (threadIdx.x >= s) ? sd[threadIdx.x - s] : 0;
    __syncthreads();
    sd[threadIdx.x] += t;
    __syncthreads();
  }
  int incl = sd[threadIdx.x];
  if (i < N_) { off[i] = base_s + incl - v; cur[i] = 0; }
  if (i == N_ - 1) off[N_] = base_s + incl;    // total = E_
}

// fill packed edge metadata: em[p] = (src, bitcast(norm)) — ONE 8B scatter per edge
__global__ __launch_bounds__(256) void k_fill(const int* __restrict__ row, const int* __restrict__ col,
                                              const int* __restrict__ off, int* __restrict__ cur,
                                              const float* __restrict__ dis,
                                              int2* __restrict__ em) {
  int e = blockIdx.x * 256 + threadIdx.x;
  if (e < E_) {
    int c = col[e], r = row[e];
    int p = off[c] + atomicAdd(&cur[c], 1);
    float w = dis[r] * dis[c];
    em[p] = make_int2(r, __float_as_int(w));
  }
}

// ---------- W fragment pre-pack: Wf[khalf][t][lane] = 8 contiguous-k fp16 of W[k][t*16+m] ----------
// B-frag layout for mfma_f32_16x16x32_f16: lane l holds B[k=(l>>4)*8+j][n=l&15], j=0..7.
__global__ __launch_bounds__(256) void k_wfrag(const float* __restrict__ W1, const float* __restrict__ W2,
                                               h8* __restrict__ Wf1, h8* __restrict__ Wf2) {
  int t0 = threadIdx.x;
  for (int w = 0; w < 2; w++) {
    const float* W = w ? W2 : W1;
    h8* Wf = w ? Wf2 : Wf1;
    for (int p = 0; p < 2; p++) {
      int fid = p * 256 + t0;          // 0..511
      int khalf = fid >> 8;
      int rem = fid & 255;
      int tt = rem >> 6;
      int lane = rem & 63;
      int kq = lane >> 4, m = lane & 15;
      h8 v;
#pragma unroll
      for (int j = 0; j < 8; j++) {
        int k = khalf * 32 + kq * 8 + j;
        v[j] = (_Float16)W[k * 64 + tt * 16 + m];
      }
      Wf[fid] = v;
    }
  }
}

// ---------- Linear: Y = X(M x 64) @ W -> fp16 node-major [n][b*16+cg] via MFMA ----------
// One wave per 16 rows. A-frag: lane holds X[r0+(l&15)][(l>>4)*8 + j].
// 8x mfma_f32_16x16x32_f16 (4 col-tiles x 2 K-halves). D: col=lane&15, row=(lane>>4)*4+reg.
// IN_F16: input rows already fp16 (layer-2 reads fp16 h1) — numerically identical to
// f32-load-then-cast since the f32 path casts to fp16 anyway.
template<int IN_F16>
__global__ __launch_bounds__(256) void k_linear(const void* __restrict__ Xv,
                                                const h8* __restrict__ Wf,
                                                _Float16* __restrict__ Y) {
  int wv = blockIdx.x * 4 + (threadIdx.x >> 6);
  int lane = threadIdx.x & 63;
  int m = lane & 15, kq = lane >> 4;
  size_t r0 = (size_t)wv * 16;
  h8 a0, a1;
  if constexpr (IN_F16) {
    const _Float16* xr = (const _Float16*)Xv + (r0 + m) * 64 + kq * 8;
    a0 = *(const h8*)(xr);
    a1 = *(const h8*)(xr + 32);
  } else {
    const float* xr = (const float*)Xv + (r0 + m) * 64 + kq * 8;
    f4 f0 = *(const f4*)(xr);
    f4 f1 = *(const f4*)(xr + 4);
    f4 f2 = *(const f4*)(xr + 32);
    f4 f3 = *(const f4*)(xr + 36);
#pragma unroll
    for (int j = 0; j < 4; j++) {
      a0[j] = (_Float16)f0[j]; a0[j + 4] = (_Float16)f1[j];
      a1[j] = (_Float16)f2[j]; a1[j + 4] = (_Float16)f3[j];
    }
  }
  f4 acc[4];
#pragma unroll
  for (int t = 0; t < 4; t++) {
    h8 b0 = Wf[t * 64 + lane];         // khalf 0
    h8 b1 = Wf[256 + t * 64 + lane];   // khalf 1
    f4 c = {0.f, 0.f, 0.f, 0.f};
    c = __builtin_amdgcn_mfma_f32_16x16x32_f16(a0, b0, c, 0, 0, 0);
    c = __builtin_amdgcn_mfma_f32_16x16x32_f16(a1, b1, c, 0, 0, 0);
    acc[t] = c;
  }
  int b  = (int)(r0 / N_);             // wave never straddles b (50000 % 16 == 0)
  int n0 = (int)(r0 - (size_t)b * N_);
#pragma unroll
  for (int t = 0; t < 4; t++) {
#pragma unroll
    for (int r = 0; r < 4; r++) {
      int n = n0 + kq * 4 + r;
      Y[(size_t)n * 256 + b * 64 + t * 16 + m] = (_Float16)acc[t][r];
    }
  }
}

// ---------- Aggregate ----------
// xw fp16 node-major [n][256] (512B rows). One wave per node.
// h8 per lane: 32 lanes cover a row, so ONE dwordx4 load instruction gathers TWO
// edges' rows (lanes 0-31 -> edge j+k, lanes 32-63 -> edge j+8+k). 8 loads in
// flight = 16 edges per memory round-trip. Cross-half merge via shfl_xor(32).
// __launch_bounds__(256,8): pin <=64 VGPR so all 32 waves/CU stay resident.
template<int OUT_F16>
__global__ __launch_bounds__(256, 8) void k_agg(const _Float16* __restrict__ xw,
                                                const int* __restrict__ off,
                                                const int2* __restrict__ em,
                                                const float* __restrict__ dis,
                                                const float* __restrict__ bias,
                                                void* __restrict__ outv) {
  int node = blockIdx.x * 4 + (threadIdx.x >> 6);
  int lane = threadIdx.x & 63;
  if (node >= N_) return;
  int l5   = lane & 31;            // h8 slot within the 512B row
  int hsel = (lane >> 5) << 3;     // edge-slot offset: 0 (half 0) / 8 (half 1)
  const h8* xp = (const h8*)xw;    // row n = xp[n*32 .. n*32+31]
  float d  = dis[node];
  float sw = d * d;                // self-loop norm
  float acc[8] = {0, 0, 0, 0, 0, 0, 0, 0};
  if (lane < 32) {                 // self row: half 0 only
    h8 sv = xp[(size_t)node * 32 + l5];
#pragma unroll
    for (int q = 0; q < 8; q++) acc[q] = (float)sv[q] * sw;
  }
  int s = off[node], e = off[node + 1];
  while (s < e) {
    int i = s + lane;
    int2 mm = (i < e) ? em[i] : make_int2(0, 0);   // pad: w=0 -> no contribution
    int er = mm.x;
    float wn = __int_as_float(mm.y);
    int c = e - s; if (c > 64) c = 64;
    for (int j = 0; j < c; j += 16) {              // 16 edges per round
      int sn[8]; float w[8];
#pragma unroll
      for (int k = 0; k < 8; k++) {
        int sl = j + hsel + k;                     // <=63 always (c<=64 -> j<=48)
        sn[k] = __shfl(er, sl);
        w[k]  = __shfl(wn, sl);
      }
      h8 v[8];
#pragma unroll
      for (int k = 0; k < 8; k++) v[k] = xp[(size_t)sn[k] * 32 + l5];
#pragma unroll
      for (int k = 0; k < 8; k++) {
        float wk = w[k];
#pragma unroll
        for (int q = 0; q < 8; q++) acc[q] += (float)v[k][q] * wk;
      }
    }
    s += 64;
  }
#pragma unroll
  for (int q = 0; q < 8; q++) acc[q] += __shfl_xor(acc[q], 32);  // merge halves
  if (lane < 32) {
    int b  = l5 >> 3;
    int d0 = (l5 & 7) * 8;
    f4 blo = *(const f4*)(bias + d0);
    f4 bhi = *(const f4*)(bias + d0 + 4);
    float r[8];
#pragma unroll
    for (int q = 0; q < 4; q++) r[q]     = tanhf(acc[q]     + blo[q]);
#pragma unroll
    for (int q = 0; q < 4; q++) r[q + 4] = tanhf(acc[q + 4] + bhi[q]);
    if constexpr (OUT_F16) {
      h8 o;
#pragma unroll
      for (int q = 0; q < 8; q++) o[q] = (_Float16)r[q];
      *(h8*)((_Float16*)outv + ((size_t)b * N_ + node) * 64 + d0) = o;
    } else {
      float* op = (float*)outv + ((size_t)b * N_ + node) * 64 + d0;
      f4 lo = {r[0], r[1], r[2], r[3]};
      f4 hi = {r[4], r[5], r[6], r[7]};
      *(f4*)op       = lo;
      *(f4*)(op + 4) = hi;
    }
  }
}

extern "C" void kernel_launch(void* const* d_in, const int* in_sizes, int n_in,
                              void* d_out, int out_size, void* d_ws, size_t ws_size,
                              hipStream_t stream) {
  const float* h  = (const float*)d_in[1];
  const int*   ei = (const int*)d_in[2];
  const float* W1 = (const float*)d_in[3];
  const float* b1 = (const float*)d_in[4];
  const float* W2 = (const float*)d_in[5];
  const float* b2 = (const float*)d_in[6];
  float* out = (float*)d_out;
  const int* row = ei;        // edge_index[0] = sources
  const int* col = ei + E_;   // edge_index[1] = targets

  // workspace layout (~33 MB)
  char* p = (char*)d_ws;
  _Float16* xw = (_Float16*)p; p += (size_t)M_ * D_ * sizeof(_Float16); // 25.6 MB, node-major [n][256]
  int2* em  = (int2*)p;   p += (size_t)E_ * sizeof(int2);               // 6.4 MB
  int*  cnt = (int*)p;    p += (size_t)N_ * sizeof(int);
  int*  off = (int*)p;    p += (size_t)(N_ + 4) * sizeof(int);
  int*  cur = (int*)p;    p += (size_t)N_ * sizeof(int);
  float* dis = (float*)p; p += (size_t)N_ * sizeof(float);
  int*  prt = (int*)p;    p += 64 * sizeof(int);
  h8*   Wf1 = (h8*)p;     p += 512 * sizeof(h8);                        // 8 KB
  h8*   Wf2 = (h8*)p;     p += 512 * sizeof(h8);                        // 8 KB
  // layer-1 output h1 is fp16 [b][n][64], staged in d_out's first 25.6 MB
  // (consumed by layer-2 k_linear before the final f32 write overwrites d_out)
  _Float16* h1 = (_Float16*)d_out;

  hipMemsetAsync(cnt, 0, N_ * sizeof(int), stream);

  k_count<<<(E_ / 4 + 255) / 256, 256, 0, stream>>>((const int4*)col, cnt);
  int nscan = (N_ + 1023) / 1024;  // 49
  k_scan_a<<<nscan, 1024, 0, stream>>>(cnt, prt, dis);
  k_scan_c<<<nscan, 1024, 0, stream>>>(cnt, prt, off, cur);
  k_fill<<<(E_ + 255) / 256, 256, 0, stream>>>(row, col, off, cur, dis, em);
  k_wfrag<<<1, 256, 0, stream>>>(W1, W2, Wf1, Wf2);

  // layer 1
  k_linear<0><<<M_ / 64, 256, 0, stream>>>(h, Wf1, xw);
  k_agg<1><<<N_ / 4, 256, 0, stream>>>(xw, off, em, dis, b1, h1);
  // layer 2
  k_linear<1><<<M_ / 64, 256, 0, stream>>>(h1, Wf2, xw);
  k_agg<0><<<N_ / 4, 256, 0, stream>>>(xw, off, em, dis, b2, out);
}

// Round 2
// 337.495 us; speedup vs baseline: 1.1644x; 1.1644x over previous
//
#include <hip/hip_runtime.h>
#include <math.h>

#define B_ 4
#define N_ 50000
#define E_ 800000
#define D_ 64
#define M_ (B_*N_)   // 200000 rows for the linear

typedef _Float16 h4 __attribute__((ext_vector_type(4)));
typedef _Float16 h8 __attribute__((ext_vector_type(8)));
typedef float    f4 __attribute__((ext_vector_type(4)));

// ---------- CSR build ----------
__global__ __launch_bounds__(256) void k_count(const int4* __restrict__ col4, int* __restrict__ cnt) {
  int e = blockIdx.x * 256 + threadIdx.x;
  if (e < E_ / 4) {
    int4 c = col4[e];
    atomicAdd(&cnt[c.x], 1);
    atomicAdd(&cnt[c.y], 1);
    atomicAdd(&cnt[c.z], 1);
    atomicAdd(&cnt[c.w], 1);
  }
}

// block-sum partials + dis = rsqrt(deg+1)
__global__ __launch_bounds__(1024) void k_scan_a(const int* __restrict__ cnt, int* __restrict__ part,
                                                 float* __restrict__ dis) {
  __shared__ int sd[1024];
  int i = blockIdx.x * 1024 + threadIdx.x;
  int v = (i < N_) ? cnt[i] : 0;
  if (i < N_) dis[i] = 1.0f / sqrtf((float)(v + 1));  // +1 self-loop
  sd[threadIdx.x] = v;
  __syncthreads();
  for (int s = 512; s > 0; s >>= 1) {
    if (threadIdx.x < s) sd[threadIdx.x] += sd[threadIdx.x + s];
    __syncthreads();
  }
  if (threadIdx.x == 0) part[blockIdx.x] = sd[0];
}

// exclusive scan -> off; also zero the fill cursors
__global__ __launch_bounds__(1024) void k_scan_c(const int* __restrict__ cnt, const int* __restrict__ part,
                                                 int* __restrict__ off, int* __restrict__ cur) {
  __shared__ int sd[1024];
  __shared__ int base_s;
  int i = blockIdx.x * 1024 + threadIdx.x;
  int v = (i < N_) ? cnt[i] : 0;
  if (threadIdx.x == 0) {
    int b = 0;
    for (int j = 0; j < (int)blockIdx.x; j++) b += part[j];
    base_s = b;
  }
  sd[threadIdx.x] = v;
  __syncthreads();
  for (int s = 1; s < 1024; s <<= 1) {
    int t = (threadIdx.x >= s) ? sd[threadIdx.x - s] : 0;
    __syncthreads();
    sd[threadIdx.x] += t;
    __syncthreads();
  }
  int incl = sd[threadIdx.x];
  if (i < N_) { off[i] = base_s + incl - v; cur[i] = 0; }
  if (i == N_ - 1) off[N_] = base_s + incl;    // total = E_
}

// fill packed edge metadata: em[p] = (src, bitcast(norm)) — ONE 8B scatter per edge
__global__ __launch_bounds__(256) void k_fill(const int* __restrict__ row, const int* __restrict__ col,
                                              const int* __restrict__ off, int* __restrict__ cur,
                                              const float* __restrict__ dis,
                                              int2* __restrict__ em) {
  int e = blockIdx.x * 256 + threadIdx.x;
  if (e < E_) {
    int c = col[e], r = row[e];
    int p = off[c] + atomicAdd(&cur[c], 1);
    float w = dis[r] * dis[c];
    em[p] = make_int2(r, __float_as_int(w));
  }
}

// ---------- W fragment pre-pack: Wf[khalf][t][lane] = 8 contiguous-k fp16 of W[k][t*16+m] ----------
// B-frag layout for mfma_f32_16x16x32_f16: lane l holds B[k=(l>>4)*8+j][n=l&15], j=0..7.
__global__ __launch_bounds__(256) void k_wfrag(const float* __restrict__ W1, const float* __restrict__ W2,
                                               h8* __restrict__ Wf1, h8* __restrict__ Wf2) {
  int t0 = threadIdx.x;
  for (int w = 0; w < 2; w++) {
    const float* W = w ? W2 : W1;
    h8* Wf = w ? Wf2 : Wf1;
    for (int p = 0; p < 2; p++) {
      int fid = p * 256 + t0;          // 0..511
      int khalf = fid >> 8;
      int rem = fid & 255;
      int tt = rem >> 6;
      int lane = rem & 63;
      int kq = lane >> 4, m = lane & 15;
      h8 v;
#pragma unroll
      for (int j = 0; j < 8; j++) {
        int k = khalf * 32 + kq * 8 + j;
        v[j] = (_Float16)W[k * 64 + tt * 16 + m];
      }
      Wf[fid] = v;
    }
  }
}

// ---------- Linear: Y = X(M x 64) @ W -> fp16 node-major [n][b*16+cg] via MFMA ----------
// One wave per 16 rows. A-frag: lane holds X[r0+(l&15)][(l>>4)*8 + j].
// 8x mfma_f32_16x16x32_f16 (4 col-tiles x 2 K-halves). D: col=lane&15, row=(lane>>4)*4+reg.
// IN_F16: input rows already fp16 (layer-2 reads fp16 h1) — numerically identical to
// f32-load-then-cast since the f32 path casts to fp16 anyway.
template<int IN_F16>
__global__ __launch_bounds__(256) void k_linear(const void* __restrict__ Xv,
                                                const h8* __restrict__ Wf,
                                                _Float16* __restrict__ Y) {
  int wv = blockIdx.x * 4 + (threadIdx.x >> 6);
  int lane = threadIdx.x & 63;
  int m = lane & 15, kq = lane >> 4;
  size_t r0 = (size_t)wv * 16;
  h8 a0, a1;
  if constexpr (IN_F16) {
    const _Float16* xr = (const _Float16*)Xv + (r0 + m) * 64 + kq * 8;
    a0 = *(const h8*)(xr);
    a1 = *(const h8*)(xr + 32);
  } else {
    const float* xr = (const float*)Xv + (r0 + m) * 64 + kq * 8;
    f4 f0 = *(const f4*)(xr);
    f4 f1 = *(const f4*)(xr + 4);
    f4 f2 = *(const f4*)(xr + 32);
    f4 f3 = *(const f4*)(xr + 36);
#pragma unroll
    for (int j = 0; j < 4; j++) {
      a0[j] = (_Float16)f0[j]; a0[j + 4] = (_Float16)f1[j];
      a1[j] = (_Float16)f2[j]; a1[j + 4] = (_Float16)f3[j];
    }
  }
  f4 acc[4];
#pragma unroll
  for (int t = 0; t < 4; t++) {
    h8 b0 = Wf[t * 64 + lane];         // khalf 0
    h8 b1 = Wf[256 + t * 64 + lane];   // khalf 1
    f4 c = {0.f, 0.f, 0.f, 0.f};
    c = __builtin_amdgcn_mfma_f32_16x16x32_f16(a0, b0, c, 0, 0, 0);
    c = __builtin_amdgcn_mfma_f32_16x16x32_f16(a1, b1, c, 0, 0, 0);
    acc[t] = c;
  }
  int b  = (int)(r0 / N_);             // wave never straddles b (50000 % 16 == 0)
  int n0 = (int)(r0 - (size_t)b * N_);
#pragma unroll
  for (int t = 0; t < 4; t++) {
#pragma unroll
    for (int r = 0; r < 4; r++) {
      int n = n0 + kq * 4 + r;
      Y[(size_t)n * 256 + b * 64 + t * 16 + m] = (_Float16)acc[t][r];
    }
  }
}

// ---------- Aggregate ----------
// xw fp16 node-major [n][256] (512B rows). One wave per node; lane owns (b=lane>>4,
// d0=(lane&15)*4): one 8B h4 per lane -> each edge gather is ONE coalesced 512B
// load per wave, and the final store is full-line (256B contiguous per b-group —
// R1's split store caused L2 RMW: WRITE_SIZE 3x). 16 gathers in flight per wave
// (R0 had 8): 32 VGPR of destinations; __launch_bounds__(256,5) caps VGPR at ~102
// (no spill) while keeping 20 waves/CU.
template<int OUT_F16>
__global__ __launch_bounds__(256, 5) void k_agg(const _Float16* __restrict__ xw,
                                                const int* __restrict__ off,
                                                const int2* __restrict__ em,
                                                const float* __restrict__ dis,
                                                const float* __restrict__ bias,
                                                void* __restrict__ outv) {
  int node = blockIdx.x * 4 + (threadIdx.x >> 6);
  int lane = threadIdx.x & 63;
  if (node >= N_) return;
  const h4* xp = (const h4*)xw;
  float d  = dis[node];
  float sw = d * d;  // self-loop norm
  f4 acc = __builtin_convertvector(xp[(size_t)node * 64 + lane], f4) * sw;
  int s = off[node], e = off[node + 1];
  while (s < e) {
    int i = s + lane;
    int2 mm = (i < e) ? em[i] : make_int2(0, 0);   // pad: w=0 -> no contribution
    int er = mm.x;
    float wn = __int_as_float(mm.y);
    int c = e - s; if (c > 64) c = 64;
    for (int j = 0; j < c; j += 16) {              // 16 edges in flight per round
      int sn[16]; float w[16];
#pragma unroll
      for (int k = 0; k < 16; k++) {               // j+k <= 48+15 = 63: always valid
        sn[k] = __shfl(er, j + k);
        w[k]  = __shfl(wn, j + k);
      }
      h4 v[16];
#pragma unroll
      for (int k = 0; k < 16; k++) v[k] = xp[(size_t)sn[k] * 64 + lane];
#pragma unroll
      for (int k = 0; k < 16; k++) acc += __builtin_convertvector(v[k], f4) * w[k];
    }
    s += 64;
  }
  int b  = lane >> 4;
  int d0 = (lane & 15) * 4;
  f4 bb = *(const f4*)(bias + d0);
  float r0 = tanhf(acc.x + bb.x);
  float r1 = tanhf(acc.y + bb.y);
  float r2 = tanhf(acc.z + bb.z);
  float r3 = tanhf(acc.w + bb.w);
  if constexpr (OUT_F16) {
    h4 o;
    o[0] = (_Float16)r0; o[1] = (_Float16)r1;
    o[2] = (_Float16)r2; o[3] = (_Float16)r3;
    // lanes 0-15 cover the full 128B fp16 row of (b=0,node) contiguously, etc.
    *(h4*)((_Float16*)outv + ((size_t)b * N_ + node) * 64 + d0) = o;
  } else {
    f4 r = {r0, r1, r2, r3};
    *(f4*)((float*)outv + ((size_t)b * N_ + node) * 64 + d0) = r;
  }
}

extern "C" void kernel_launch(void* const* d_in, const int* in_sizes, int n_in,
                              void* d_out, int out_size, void* d_ws, size_t ws_size,
                              hipStream_t stream) {
  const float* h  = (const float*)d_in[1];
  const int*   ei = (const int*)d_in[2];
  const float* W1 = (const float*)d_in[3];
  const float* b1 = (const float*)d_in[4];
  const float* W2 = (const float*)d_in[5];
  const float* b2 = (const float*)d_in[6];
  float* out = (float*)d_out;
  const int* row = ei;        // edge_index[0] = sources
  const int* col = ei + E_;   // edge_index[1] = targets

  // workspace layout (~33 MB)
  char* p = (char*)d_ws;
  _Float16* xw = (_Float16*)p; p += (size_t)M_ * D_ * sizeof(_Float16); // 25.6 MB, node-major [n][256]
  int2* em  = (int2*)p;   p += (size_t)E_ * sizeof(int2);               // 6.4 MB
  int*  cnt = (int*)p;    p += (size_t)N_ * sizeof(int);
  int*  off = (int*)p;    p += (size_t)(N_ + 4) * sizeof(int);
  int*  cur = (int*)p;    p += (size_t)N_ * sizeof(int);
  float* dis = (float*)p; p += (size_t)N_ * sizeof(float);
  int*  prt = (int*)p;    p += 64 * sizeof(int);
  h8*   Wf1 = (h8*)p;     p += 512 * sizeof(h8);                        // 8 KB
  h8*   Wf2 = (h8*)p;     p += 512 * sizeof(h8);                        // 8 KB
  // layer-1 output h1 is fp16 [b][n][64], staged in d_out's first 25.6 MB
  // (consumed by layer-2 k_linear before the final f32 write overwrites d_out)
  _Float16* h1 = (_Float16*)d_out;

  hipMemsetAsync(cnt, 0, N_ * sizeof(int), stream);

  k_count<<<(E_ / 4 + 255) / 256, 256, 0, stream>>>((const int4*)col, cnt);
  int nscan = (N_ + 1023) / 1024;  // 49
  k_scan_a<<<nscan, 1024, 0, stream>>>(cnt, prt, dis);
  k_scan_c<<<nscan, 1024, 0, stream>>>(cnt, prt, off, cur);
  k_fill<<<(E_ + 255) / 256, 256, 0, stream>>>(row, col, off, cur, dis, em);
  k_wfrag<<<1, 256, 0, stream>>>(W1, W2, Wf1, Wf2);

  // layer 1
  k_linear<0><<<M_ / 64, 256, 0, stream>>>(h, Wf1, xw);
  k_agg<1><<<N_ / 4, 256, 0, stream>>>(xw, off, em, dis, b1, h1);
  // layer 2
  k_linear<1><<<M_ / 64, 256, 0, stream>>>(h1, Wf2, xw);
  k_agg<0><<<N_ / 4, 256, 0, stream>>>(xw, off, em, dis, b2, out);
}

// Round 3
// 334.406 us; speedup vs baseline: 1.1751x; 1.0092x over previous
//
#include <hip/hip_runtime.h>
#include <math.h>

#define B_ 4
#define N_ 50000
#define E_ 800000
#define D_ 64
#define M_ (B_*N_)   // 200000 rows for the linear

typedef _Float16 h4 __attribute__((ext_vector_type(4)));
typedef _Float16 h8 __attribute__((ext_vector_type(8)));
typedef float    f4 __attribute__((ext_vector_type(4)));

// ---------- CSR build ----------
__global__ __launch_bounds__(256) void k_count(const int4* __restrict__ col4, int* __restrict__ cnt) {
  int e = blockIdx.x * 256 + threadIdx.x;
  if (e < E_ / 4) {
    int4 c = col4[e];
    atomicAdd(&cnt[c.x], 1);
    atomicAdd(&cnt[c.y], 1);
    atomicAdd(&cnt[c.z], 1);
    atomicAdd(&cnt[c.w], 1);
  }
}

// block-sum partials + dis = rsqrt(deg+1)
__global__ __launch_bounds__(1024) void k_scan_a(const int* __restrict__ cnt, int* __restrict__ part,
                                                 float* __restrict__ dis) {
  __shared__ int sd[1024];
  int i = blockIdx.x * 1024 + threadIdx.x;
  int v = (i < N_) ? cnt[i] : 0;
  if (i < N_) dis[i] = 1.0f / sqrtf((float)(v + 1));  // +1 self-loop
  sd[threadIdx.x] = v;
  __syncthreads();
  for (int s = 512; s > 0; s >>= 1) {
    if (threadIdx.x < s) sd[threadIdx.x] += sd[threadIdx.x + s];
    __syncthreads();
  }
  if (threadIdx.x == 0) part[blockIdx.x] = sd[0];
}

// exclusive scan -> off; also zero the fill cursors
__global__ __launch_bounds__(1024) void k_scan_c(const int* __restrict__ cnt, const int* __restrict__ part,
                                                 int* __restrict__ off, int* __restrict__ cur) {
  __shared__ int sd[1024];
  __shared__ int base_s;
  int i = blockIdx.x * 1024 + threadIdx.x;
  int v = (i < N_) ? cnt[i] : 0;
  if (threadIdx.x == 0) {
    int b = 0;
    for (int j = 0; j < (int)blockIdx.x; j++) b += part[j];
    base_s = b;
  }
  sd[threadIdx.x] = v;
  __syncthreads();
  for (int s = 1; s < 1024; s <<= 1) {
    int t = (threadIdx.x >= s) ? sd[threadIdx.x - s] : 0;
    __syncthreads();
    sd[threadIdx.x] += t;
    __syncthreads();
  }
  int incl = sd[threadIdx.x];
  if (i < N_) { off[i] = base_s + incl - v; cur[i] = 0; }
  if (i == N_ - 1) off[N_] = base_s + incl;    // total = E_
}

// fill packed edge metadata: em[p] = (row*512 byte offset, bitcast(norm))
// Pre-multiplied row offset enables pure SCALAR gather-base math in k_agg.
__global__ __launch_bounds__(256) void k_fill(const int* __restrict__ row, const int* __restrict__ col,
                                              const int* __restrict__ off, int* __restrict__ cur,
                                              const float* __restrict__ dis,
                                              int2* __restrict__ em) {
  int e = blockIdx.x * 256 + threadIdx.x;
  if (e < E_) {
    int c = col[e], r = row[e];
    int p = off[c] + atomicAdd(&cur[c], 1);
    float w = dis[r] * dis[c];
    em[p] = make_int2(r << 9, __float_as_int(w));   // r*512 = byte offset of row r
  }
}

// ---------- W fragment pre-pack: Wf[khalf][t][lane] = 8 contiguous-k fp16 of W[k][t*16+m] ----------
// B-frag layout for mfma_f32_16x16x32_f16: lane l holds B[k=(l>>4)*8+j][n=l&15], j=0..7.
__global__ __launch_bounds__(256) void k_wfrag(const float* __restrict__ W1, const float* __restrict__ W2,
                                               h8* __restrict__ Wf1, h8* __restrict__ Wf2) {
  int t0 = threadIdx.x;
  for (int w = 0; w < 2; w++) {
    const float* W = w ? W2 : W1;
    h8* Wf = w ? Wf2 : Wf1;
    for (int p = 0; p < 2; p++) {
      int fid = p * 256 + t0;          // 0..511
      int khalf = fid >> 8;
      int rem = fid & 255;
      int tt = rem >> 6;
      int lane = rem & 63;
      int kq = lane >> 4, m = lane & 15;
      h8 v;
#pragma unroll
      for (int j = 0; j < 8; j++) {
        int k = khalf * 32 + kq * 8 + j;
        v[j] = (_Float16)W[k * 64 + tt * 16 + m];
      }
      Wf[fid] = v;
    }
  }
}

// ---------- Linear: Y = X(M x 64) @ W -> fp16 node-major [n][b*16+cg] via MFMA ----------
// One wave per 16 rows. A-frag: lane holds X[r0+(l&15)][(l>>4)*8 + j].
// 8x mfma_f32_16x16x32_f16 (4 col-tiles x 2 K-halves). D: col=lane&15, row=(lane>>4)*4+reg.
template<int IN_F16>
__global__ __launch_bounds__(256) void k_linear(const void* __restrict__ Xv,
                                                const h8* __restrict__ Wf,
                                                _Float16* __restrict__ Y) {
  int wv = blockIdx.x * 4 + (threadIdx.x >> 6);
  int lane = threadIdx.x & 63;
  int m = lane & 15, kq = lane >> 4;
  size_t r0 = (size_t)wv * 16;
  h8 a0, a1;
  if constexpr (IN_F16) {
    const _Float16* xr = (const _Float16*)Xv + (r0 + m) * 64 + kq * 8;
    a0 = *(const h8*)(xr);
    a1 = *(const h8*)(xr + 32);
  } else {
    const float* xr = (const float*)Xv + (r0 + m) * 64 + kq * 8;
    f4 f0 = *(const f4*)(xr);
    f4 f1 = *(const f4*)(xr + 4);
    f4 f2 = *(const f4*)(xr + 32);
    f4 f3 = *(const f4*)(xr + 36);
#pragma unroll
    for (int j = 0; j < 4; j++) {
      a0[j] = (_Float16)f0[j]; a0[j + 4] = (_Float16)f1[j];
      a1[j] = (_Float16)f2[j]; a1[j + 4] = (_Float16)f3[j];
    }
  }
  f4 acc[4];
#pragma unroll
  for (int t = 0; t < 4; t++) {
    h8 b0 = Wf[t * 64 + lane];         // khalf 0
    h8 b1 = Wf[256 + t * 64 + lane];   // khalf 1
    f4 c = {0.f, 0.f, 0.f, 0.f};
    c = __builtin_amdgcn_mfma_f32_16x16x32_f16(a0, b0, c, 0, 0, 0);
    c = __builtin_amdgcn_mfma_f32_16x16x32_f16(a1, b1, c, 0, 0, 0);
    acc[t] = c;
  }
  int b  = (int)(r0 / N_);             // wave never straddles b (50000 % 16 == 0)
  int n0 = (int)(r0 - (size_t)b * N_);
#pragma unroll
  for (int t = 0; t < 4; t++) {
#pragma unroll
    for (int r = 0; r < 4; r++) {
      int n = n0 + kq * 4 + r;
      Y[(size_t)n * 256 + b * 64 + t * 16 + m] = (_Float16)acc[t][r];
    }
  }
}

// ---------- Aggregate (scalarized edge stream) ----------
// xw fp16 node-major [n][256] (512B rows). One wave per node; lane owns (b=lane>>4,
// d0=(lane&15)*4): 8B per lane -> each edge gather is ONE coalesced 512B load.
// Edge metadata index j is made wave-uniform via readfirstlane(off[node]) so em[j]
// is a provably-uniform load -> s_load_dwordx2 on the SCALAR pipe, and the gather
// base (xw + row*512, premultiplied in k_fill) is computed with scalar adds.
// Per-edge cost: 1 s_load + 1 global_load_dwordx2 + 4 cvt + 4 fmac. No shuffles,
// no per-edge 64-bit VALU address math, no chunk/pad logic.
template<int OUT_F16>
__global__ __launch_bounds__(512) void k_agg(const _Float16* __restrict__ xw,
                                             const int* __restrict__ off,
                                             const int2* __restrict__ em,
                                             const float* __restrict__ bias,
                                             void* __restrict__ outv) {
  int node = blockIdx.x * 8 + (threadIdx.x >> 6);
  int lane = threadIdx.x & 63;
  const char* xb = (const char*)xw + (size_t)(lane * 8);  // lane's slot in any row
  int s0 = __builtin_amdgcn_readfirstlane(off[node]);
  int e0 = __builtin_amdgcn_readfirstlane(off[node + 1]);
  float sw = 1.0f / (float)(e0 - s0 + 1);                 // dis[node]^2 (self norm)
  h4 sv = *(const h4*)(xb + ((size_t)node << 9));
  f4 acc = __builtin_convertvector(sv, f4) * sw;
#define EDGE_(mm) do { \
    h4 v_ = *(const h4*)(xb + (unsigned)(mm).x); \
    acc += __builtin_convertvector(v_, f4) * __int_as_float((mm).y); \
  } while (0)
  int j = s0;
  for (; j + 8 <= e0; j += 8) {
    int2 m0 = em[j],     m1 = em[j + 1], m2 = em[j + 2], m3 = em[j + 3];
    int2 m4 = em[j + 4], m5 = em[j + 5], m6 = em[j + 6], m7 = em[j + 7];
    EDGE_(m0); EDGE_(m1); EDGE_(m2); EDGE_(m3);
    EDGE_(m4); EDGE_(m5); EDGE_(m6); EDGE_(m7);
  }
  for (; j < e0; ++j) { int2 m = em[j]; EDGE_(m); }
#undef EDGE_
  int b  = lane >> 4;
  int d0 = (lane & 15) * 4;
  f4 bb = *(const f4*)(bias + d0);
  float r0 = tanhf(acc.x + bb.x);
  float r1 = tanhf(acc.y + bb.y);
  float r2 = tanhf(acc.z + bb.z);
  float r3 = tanhf(acc.w + bb.w);
  if constexpr (OUT_F16) {
    h4 o;
    o[0] = (_Float16)r0; o[1] = (_Float16)r1;
    o[2] = (_Float16)r2; o[3] = (_Float16)r3;
    // lanes 0-15 cover the full 128B fp16 row of (b=0,node) contiguously, etc.
    *(h4*)((_Float16*)outv + ((size_t)b * N_ + node) * 64 + d0) = o;
  } else {
    f4 r = {r0, r1, r2, r3};
    *(f4*)((float*)outv + ((size_t)b * N_ + node) * 64 + d0) = r;
  }
}

extern "C" void kernel_launch(void* const* d_in, const int* in_sizes, int n_in,
                              void* d_out, int out_size, void* d_ws, size_t ws_size,
                              hipStream_t stream) {
  const float* h  = (const float*)d_in[1];
  const int*   ei = (const int*)d_in[2];
  const float* W1 = (const float*)d_in[3];
  const float* b1 = (const float*)d_in[4];
  const float* W2 = (const float*)d_in[5];
  const float* b2 = (const float*)d_in[6];
  float* out = (float*)d_out;
  const int* row = ei;        // edge_index[0] = sources
  const int* col = ei + E_;   // edge_index[1] = targets

  // workspace layout (~33 MB)
  char* p = (char*)d_ws;
  _Float16* xw = (_Float16*)p; p += (size_t)M_ * D_ * sizeof(_Float16); // 25.6 MB, node-major [n][256]
  int2* em  = (int2*)p;   p += (size_t)E_ * sizeof(int2);               // 6.4 MB
  int*  cnt = (int*)p;    p += (size_t)N_ * sizeof(int);
  int*  off = (int*)p;    p += (size_t)(N_ + 4) * sizeof(int);
  int*  cur = (int*)p;    p += (size_t)N_ * sizeof(int);
  float* dis = (float*)p; p += (size_t)N_ * sizeof(float);
  int*  prt = (int*)p;    p += 64 * sizeof(int);
  h8*   Wf1 = (h8*)p;     p += 512 * sizeof(h8);                        // 8 KB
  h8*   Wf2 = (h8*)p;     p += 512 * sizeof(h8);                        // 8 KB
  // layer-1 output h1 is fp16 [b][n][64], staged in d_out's first 25.6 MB
  // (consumed by layer-2 k_linear before the final f32 write overwrites d_out)
  _Float16* h1 = (_Float16*)d_out;

  hipMemsetAsync(cnt, 0, N_ * sizeof(int), stream);

  k_count<<<(E_ / 4 + 255) / 256, 256, 0, stream>>>((const int4*)col, cnt);
  int nscan = (N_ + 1023) / 1024;  // 49
  k_scan_a<<<nscan, 1024, 0, stream>>>(cnt, prt, dis);
  k_scan_c<<<nscan, 1024, 0, stream>>>(cnt, prt, off, cur);
  k_fill<<<(E_ + 255) / 256, 256, 0, stream>>>(row, col, off, cur, dis, em);
  k_wfrag<<<1, 256, 0, stream>>>(W1, W2, Wf1, Wf2);

  // layer 1
  k_linear<0><<<M_ / 64, 256, 0, stream>>>(h, Wf1, xw);
  k_agg<1><<<N_ / 8, 512, 0, stream>>>(xw, off, em, b1, h1);
  // layer 2
  k_linear<1><<<M_ / 64, 256, 0, stream>>>(h1, Wf2, xw);
  k_agg<0><<<N_ / 8, 512, 0, stream>>>(xw, off, em, b2, out);
}